// Round 3
// baseline (760.109 us; speedup 1.0000x reference)
//
#include <hip/hip_runtime.h>
#include <hip/hip_bf16.h>
#include <math.h>

// ===========================================================================
// f64-accumulate / f32-storage-grid pipeline.
// The np reference is float32: every materialized array (conv maps, h1, last,
// nrm, gram, fid) lives on the f32 grid, and threshold compares use
// float(0.8)/float(0.6). We accumulate in f64 (unbiased center of any f32
// accumulation ordering) and round to f32 at every boundary the reference
// materializes, comparing fid (f32) against 0.8f/0.6f. This captures the
// SHARED error component of the np/jax references at the hard thresholds.
// ===========================================================================

// ---------------------------------------------------------------------------
// Fused CNN: conv(1->8,3x3,SAME)+relu+pool2 -> conv(8->16,3x3,SAME)+relu+pool2
// f64 accumulation, f32 storage at each conv boundary (sF, flat).
// x: [1024,1,64,64] -> flat: [1024,4096] f32  (flatten c*256 + y*16 + x)
// ---------------------------------------------------------------------------
__global__ __launch_bounds__(256) void conv_fused(
    const float* __restrict__ x,
    const float* __restrict__ cw1, const float* __restrict__ cb1,
    const float* __restrict__ cw2, const float* __restrict__ cb2,
    float* __restrict__ flat) {
  __shared__ float sX[66 * 66];       // padded input
  __shared__ float sF[8 * 34 * 34];   // padded conv1 output (f32 grid), 37 KB
  __shared__ float sW1[72];
  __shared__ float sW2[1152];
  __shared__ float sB1[8];
  __shared__ float sB2[16];

  const int b = blockIdx.x;
  const int t = threadIdx.x;

  for (int i = t; i < 66 * 66; i += 256) sX[i] = 0.0f;
  for (int i = t; i < 8 * 34 * 34; i += 256) sF[i] = 0.0f;
  if (t < 72) sW1[t] = cw1[t];
  for (int i = t; i < 1152; i += 256) sW2[i] = cw2[i];
  if (t < 8)  sB1[t] = cb1[t];
  if (t < 16) sB2[t] = cb2[t];
  __syncthreads();

  const float* xb = x + (size_t)b * 4096;
  for (int i = t; i < 4096; i += 256)
    sX[((i >> 6) + 1) * 66 + (i & 63) + 1] = xb[i];
  __syncthreads();

  // ---- conv1 (f64 acc) + bias + relu + pool -> sF (f32 grid) ----
  // Rounding after pool+relu == reference's round-then-pool (monotone).
  for (int p = t; p < 8192; p += 256) {
    const int ch = p >> 10, pos = p & 1023;
    const int py1 = pos >> 5, px1 = pos & 31;
    double best = -1e300;
#pragma unroll
    for (int dy = 0; dy < 2; ++dy) {
#pragma unroll
      for (int dx = 0; dx < 2; ++dx) {
        const int y = 2 * py1 + dy, xx = 2 * px1 + dx;
        double s = 0.0;
#pragma unroll
        for (int ky = 0; ky < 3; ++ky)
#pragma unroll
          for (int kx = 0; kx < 3; ++kx)
            s = fma((double)sX[(y + ky) * 66 + xx + kx],
                    (double)sW1[ch * 9 + ky * 3 + kx], s);
        best = fmax(best, s);
      }
    }
    sF[ch * 1156 + (py1 + 1) * 34 + px1 + 1] =
        (float)fmax(best + (double)sB1[ch], 0.0);
  }
  __syncthreads();

  // ---- conv2 (f64 acc over f32 sF) + bias + relu + pool -> flat (f32) ----
  const int py = t >> 4, px = t & 15;  // this thread's pooled output pixel
  for (int oh = 0; oh < 2; ++oh) {     // output channels [8*oh, 8*oh+8)
    double acc[8][4];
#pragma unroll
    for (int o = 0; o < 8; ++o)
#pragma unroll
      for (int q = 0; q < 4; ++q) acc[o][q] = 0.0;

#pragma unroll
    for (int ic = 0; ic < 8; ++ic) {
      double r[4][4];
#pragma unroll
      for (int iy = 0; iy < 4; ++iy)
#pragma unroll
        for (int ix = 0; ix < 4; ++ix)
          r[iy][ix] = (double)sF[ic * 1156 + (2 * py + iy) * 34 + 2 * px + ix];
#pragma unroll
      for (int o = 0; o < 8; ++o) {
        const float* w = &sW2[(oh * 8 + o) * 72 + ic * 9];
        double w9[9];
#pragma unroll
        for (int k = 0; k < 9; ++k) w9[k] = (double)w[k];
#pragma unroll
        for (int dy = 0; dy < 2; ++dy)
#pragma unroll
          for (int dx = 0; dx < 2; ++dx) {
            double s = acc[o][dy * 2 + dx];
#pragma unroll
            for (int ky = 0; ky < 3; ++ky)
#pragma unroll
              for (int kx = 0; kx < 3; ++kx)
                s = fma(r[dy + ky][dx + kx], w9[ky * 3 + kx], s);
            acc[o][dy * 2 + dx] = s;
          }
      }
    }

    float* ob = flat + (size_t)b * 4096 + py * 16 + px;
#pragma unroll
    for (int o = 0; o < 8; ++o) {
      const int oc = oh * 8 + o;
      double best =
          fmax(fmax(acc[o][0], acc[o][1]), fmax(acc[o][2], acc[o][3]));
      ob[oc * 256] = (float)fmax(best + (double)sB2[oc], 0.0);
    }
  }
}

// ---------------------------------------------------------------------------
// NT GEMM, f32 in / f64 accumulate / f32-grid tanh epilogue:
// zg = f32(acc); z = zg + bias (f32 add); C = f32(tanh(f64(z)))
// ---------------------------------------------------------------------------
__global__ __launch_bounds__(256) void gemm_tanh(
    const float* __restrict__ A, const float* __restrict__ B,
    const float* __restrict__ bias, float* __restrict__ C,
    int M, int N, int K) {
  __shared__ float As[16][64];
  __shared__ float Bs[16][64];

  const int t = threadIdx.x;
  const int m0 = blockIdx.y * 64;
  const int n0 = blockIdx.x * 64;
  const int lm = t >> 2;
  const int lk = (t & 3) * 4;
  const int ty = t >> 4;
  const int tx = t & 15;

  double acc[4][4];
#pragma unroll
  for (int i = 0; i < 4; ++i)
#pragma unroll
    for (int j = 0; j < 4; ++j) acc[i][j] = 0.0;

  for (int k0 = 0; k0 < K; k0 += 16) {
    const float4 av = *(const float4*)&A[(size_t)(m0 + lm) * K + k0 + lk];
    const float4 bv = *(const float4*)&B[(size_t)(n0 + lm) * K + k0 + lk];
    __syncthreads();
    As[lk + 0][lm] = av.x; As[lk + 1][lm] = av.y;
    As[lk + 2][lm] = av.z; As[lk + 3][lm] = av.w;
    Bs[lk + 0][lm] = bv.x; Bs[lk + 1][lm] = bv.y;
    Bs[lk + 2][lm] = bv.z; Bs[lk + 3][lm] = bv.w;
    __syncthreads();
#pragma unroll
    for (int k = 0; k < 16; ++k) {
      double a[4], b[4];
#pragma unroll
      for (int i = 0; i < 4; ++i) a[i] = (double)As[k][ty * 4 + i];
#pragma unroll
      for (int j = 0; j < 4; ++j) b[j] = (double)Bs[k][tx * 4 + j];
#pragma unroll
      for (int i = 0; i < 4; ++i)
#pragma unroll
        for (int j = 0; j < 4; ++j) acc[i][j] = fma(a[i], b[j], acc[i][j]);
    }
  }

  const int mBase = m0 + ty * 4;
  const int nBase = n0 + tx * 4;
#pragma unroll
  for (int i = 0; i < 4; ++i)
#pragma unroll
    for (int j = 0; j < 4; ++j) {
      const float zg = (float)acc[i][j];       // f32 matmul-output grid
      const float z = zg + bias[nBase + j];    // f32 bias add
      C[(size_t)(mBase + i) * N + nBase + j] = (float)tanh((double)z);
    }
}

// ---------------------------------------------------------------------------
// Gram + threshold adjacency on the reference's f32 grid:
// g = f32(f64-dot); fid = g*g (f32); adj per 0.8f/0.6f cutoffs; diag zero.
// ---------------------------------------------------------------------------
__global__ __launch_bounds__(256) void gram_adj(
    const float* __restrict__ Nrm, float* __restrict__ adj, int Msz, int K) {
  __shared__ float As[16][64];
  __shared__ float Bs[16][64];

  const int t = threadIdx.x;
  const int m0 = blockIdx.y * 64;
  const int n0 = blockIdx.x * 64;
  const int lm = t >> 2;
  const int lk = (t & 3) * 4;
  const int ty = t >> 4;
  const int tx = t & 15;

  double acc[4][4];
#pragma unroll
  for (int i = 0; i < 4; ++i)
#pragma unroll
    for (int j = 0; j < 4; ++j) acc[i][j] = 0.0;

  for (int k0 = 0; k0 < K; k0 += 16) {
    const float4 av = *(const float4*)&Nrm[(size_t)(m0 + lm) * K + k0 + lk];
    const float4 bv = *(const float4*)&Nrm[(size_t)(n0 + lm) * K + k0 + lk];
    __syncthreads();
    As[lk + 0][lm] = av.x; As[lk + 1][lm] = av.y;
    As[lk + 2][lm] = av.z; As[lk + 3][lm] = av.w;
    Bs[lk + 0][lm] = bv.x; Bs[lk + 1][lm] = bv.y;
    Bs[lk + 2][lm] = bv.z; Bs[lk + 3][lm] = bv.w;
    __syncthreads();
#pragma unroll
    for (int k = 0; k < 16; ++k) {
      double a[4], b[4];
#pragma unroll
      for (int i = 0; i < 4; ++i) a[i] = (double)As[k][ty * 4 + i];
#pragma unroll
      for (int j = 0; j < 4; ++j) b[j] = (double)Bs[k][tx * 4 + j];
#pragma unroll
      for (int i = 0; i < 4; ++i)
#pragma unroll
        for (int j = 0; j < 4; ++j) acc[i][j] = fma(a[i], b[j], acc[i][j]);
    }
  }

  const int mBase = m0 + ty * 4;
  const int nBase = n0 + tx * 4;
#pragma unroll
  for (int i = 0; i < 4; ++i)
#pragma unroll
    for (int j = 0; j < 4; ++j) {
      const float g = (float)acc[i][j];  // f32 Gram grid
      const float fid = g * g;           // f32 square
      float v = (fid >= 0.8f) ? 1.0f : ((fid >= 0.6f) ? 0.5f : 0.0f);
      if (mBase + i == nBase + j) v = 0.0f;
      adj[(size_t)(mBase + i) * Msz + nBase + j] = v;
    }
}

// ---------------------------------------------------------------------------
// Row L2-normalize on the f32 grid: sq = v*v (f32); sum in f64;
// s32 = f32(sum); n = sqrtf(s32); den = n + 1e-12f; nrm = v / den.
// ---------------------------------------------------------------------------
__global__ __launch_bounds__(256) void rownorm(
    const float* __restrict__ last, float* __restrict__ nrm) {
  const int b = blockIdx.x;
  const int t = threadIdx.x;
  const float v = last[(size_t)b * 256 + t];
  const float sq = v * v;                 // f32 elementwise square (shared grid)
  double s = (double)sq;
#pragma unroll
  for (int o = 32; o > 0; o >>= 1) s += __shfl_down(s, o);
  __shared__ double red[4];
  if ((t & 63) == 0) red[t >> 6] = s;
  __syncthreads();
  const double total = red[0] + red[1] + red[2] + red[3];
  const float s32 = (float)total;
  const float den = sqrtf(s32) + 1e-12f;
  nrm[(size_t)b * 256 + t] = v / den;
}

// ---------------------------------------------------------------------------
// BatchNorm1d training-mode; f64 stats (loose 0.2 threshold, no razor here).
// ---------------------------------------------------------------------------
__global__ __launch_bounds__(256) void bn_stats(
    const float* __restrict__ last, const float* __restrict__ gamma,
    const float* __restrict__ beta, float* __restrict__ out) {
  const int j = blockIdx.x;
  const int t = threadIdx.x;
  double v[4];
  double s = 0.0;
#pragma unroll
  for (int i = 0; i < 4; ++i) {
    v[i] = (double)last[(size_t)(i * 256 + t) * 256 + j];
    s += v[i];
  }
#pragma unroll
  for (int o = 32; o > 0; o >>= 1) s += __shfl_down(s, o);
  __shared__ double red[4];
  if ((t & 63) == 0) red[t >> 6] = s;
  __syncthreads();
  const double mean = (red[0] + red[1] + red[2] + red[3]) * (1.0 / 1024.0);
  double q = 0.0;
#pragma unroll
  for (int i = 0; i < 4; ++i) {
    const double d = v[i] - mean;
    q += d * d;
  }
#pragma unroll
  for (int o = 32; o > 0; o >>= 1) q += __shfl_down(q, o);
  __syncthreads();
  if ((t & 63) == 0) red[t >> 6] = q;
  __syncthreads();
  const double var = (red[0] + red[1] + red[2] + red[3]) * (1.0 / 1024.0);
  const double g = (double)gamma[j] / sqrt(var + 1e-5);
  const double be = (double)beta[j];
#pragma unroll
  for (int i = 0; i < 4; ++i)
    out[(size_t)(i * 256 + t) * 256 + j] = (float)((v[i] - mean) * g + be);
}

// ---------------------------------------------------------------------------
extern "C" void kernel_launch(void* const* d_in, const int* in_sizes, int n_in,
                              void* d_out, int out_size, void* d_ws,
                              size_t ws_size, hipStream_t stream) {
  const float* x     = (const float*)d_in[0];
  const float* cw1   = (const float*)d_in[1];
  const float* cb1   = (const float*)d_in[2];
  const float* cw2   = (const float*)d_in[3];
  const float* cb2   = (const float*)d_in[4];
  const float* w1    = (const float*)d_in[5];   // [1024,4096]
  const float* b1    = (const float*)d_in[6];
  const float* w2    = (const float*)d_in[7];   // [256,1024]
  const float* b2    = (const float*)d_in[8];
  const float* gamma = (const float*)d_in[9];
  const float* beta  = (const float*)d_in[10];

  float* outp = (float*)d_out;            // [1024,256]
  float* adj  = outp + 1024 * 256;        // [1024,1024]

  float* ws   = (float*)d_ws;
  float* flat = ws;                       // [1024,4096] 16.8 MB
  float* h1   = ws + 4194304;             // [1024,1024]  4.2 MB
  float* last = ws + 5242880;             // [1024,256]   1.0 MB
  float* nrm  = ws + 5505024;             // [1024,256]   1.0 MB

  conv_fused<<<1024, 256, 0, stream>>>(x, cw1, cb1, cw2, cb2, flat);

  // h1 = tanh(flat @ w1^T + b1)   [1024,1024], K=4096
  gemm_tanh<<<dim3(16, 16), 256, 0, stream>>>(flat, w1, b1, h1,
                                              1024, 1024, 4096);
  // last = tanh(h1 @ w2^T + b2)   [1024,256], K=1024
  gemm_tanh<<<dim3(4, 16), 256, 0, stream>>>(h1, w2, b2, last,
                                             1024, 256, 1024);
  rownorm<<<1024, 256, 0, stream>>>(last, nrm);

  // adj = thr((nrm @ nrm^T)^2 on f32 grid), zero diag
  gram_adj<<<dim3(16, 16), 256, 0, stream>>>(nrm, adj, 1024, 256);

  bn_stats<<<256, 256, 0, stream>>>(last, gamma, beta, outp);
}

// Round 4
// 452.343 us; speedup vs baseline: 1.6804x; 1.6804x over previous
//
#include <hip/hip_runtime.h>
#include <hip/hip_bf16.h>
#include <math.h>

// ===========================================================================
// f64-accumulate / f32-storage-grid pipeline (R2 numerics, proven passing),
// with split-K GEMMs for occupancy. R2 GEMM1 ran at 1 block/CU (4 waves),
// VALUBusy 37%. Split-K x4 -> 1024 blocks (16 waves/CU). f64 partial sums
// reduced in fixed order; reordering error ~1e-16 rel, five orders below the
// demonstrated adjacency razor margin.
// ===========================================================================

// ---------------------------------------------------------------------------
// Fused CNN (unchanged from R2): conv1+relu+pool -> conv2+relu+pool,
// f64 accumulate, f32 grid at both conv boundaries.
// ---------------------------------------------------------------------------
__global__ __launch_bounds__(256) void conv_fused(
    const float* __restrict__ x,
    const float* __restrict__ cw1, const float* __restrict__ cb1,
    const float* __restrict__ cw2, const float* __restrict__ cb2,
    float* __restrict__ flat) {
  __shared__ float sX[66 * 66];
  __shared__ float sF[8 * 34 * 34];
  __shared__ float sW1[72];
  __shared__ float sW2[1152];
  __shared__ float sB1[8];
  __shared__ float sB2[16];

  const int b = blockIdx.x;
  const int t = threadIdx.x;

  for (int i = t; i < 66 * 66; i += 256) sX[i] = 0.0f;
  for (int i = t; i < 8 * 34 * 34; i += 256) sF[i] = 0.0f;
  if (t < 72) sW1[t] = cw1[t];
  for (int i = t; i < 1152; i += 256) sW2[i] = cw2[i];
  if (t < 8)  sB1[t] = cb1[t];
  if (t < 16) sB2[t] = cb2[t];
  __syncthreads();

  const float* xb = x + (size_t)b * 4096;
  for (int i = t; i < 4096; i += 256)
    sX[((i >> 6) + 1) * 66 + (i & 63) + 1] = xb[i];
  __syncthreads();

  for (int p = t; p < 8192; p += 256) {
    const int ch = p >> 10, pos = p & 1023;
    const int py1 = pos >> 5, px1 = pos & 31;
    double best = -1e300;
#pragma unroll
    for (int dy = 0; dy < 2; ++dy) {
#pragma unroll
      for (int dx = 0; dx < 2; ++dx) {
        const int y = 2 * py1 + dy, xx = 2 * px1 + dx;
        double s = 0.0;
#pragma unroll
        for (int ky = 0; ky < 3; ++ky)
#pragma unroll
          for (int kx = 0; kx < 3; ++kx)
            s = fma((double)sX[(y + ky) * 66 + xx + kx],
                    (double)sW1[ch * 9 + ky * 3 + kx], s);
        best = fmax(best, s);
      }
    }
    sF[ch * 1156 + (py1 + 1) * 34 + px1 + 1] =
        (float)fmax(best + (double)sB1[ch], 0.0);
  }
  __syncthreads();

  const int py = t >> 4, px = t & 15;
  for (int oh = 0; oh < 2; ++oh) {
    double acc[8][4];
#pragma unroll
    for (int o = 0; o < 8; ++o)
#pragma unroll
      for (int q = 0; q < 4; ++q) acc[o][q] = 0.0;

#pragma unroll
    for (int ic = 0; ic < 8; ++ic) {
      double r[4][4];
#pragma unroll
      for (int iy = 0; iy < 4; ++iy)
#pragma unroll
        for (int ix = 0; ix < 4; ++ix)
          r[iy][ix] = (double)sF[ic * 1156 + (2 * py + iy) * 34 + 2 * px + ix];
#pragma unroll
      for (int o = 0; o < 8; ++o) {
        const float* w = &sW2[(oh * 8 + o) * 72 + ic * 9];
        double w9[9];
#pragma unroll
        for (int k = 0; k < 9; ++k) w9[k] = (double)w[k];
#pragma unroll
        for (int dy = 0; dy < 2; ++dy)
#pragma unroll
          for (int dx = 0; dx < 2; ++dx) {
            double s = acc[o][dy * 2 + dx];
#pragma unroll
            for (int ky = 0; ky < 3; ++ky)
#pragma unroll
              for (int kx = 0; kx < 3; ++kx)
                s = fma(r[dy + ky][dx + kx], w9[ky * 3 + kx], s);
            acc[o][dy * 2 + dx] = s;
          }
      }
    }

    float* ob = flat + (size_t)b * 4096 + py * 16 + px;
#pragma unroll
    for (int o = 0; o < 8; ++o) {
      const int oc = oh * 8 + o;
      double best =
          fmax(fmax(acc[o][0], acc[o][1]), fmax(acc[o][2], acc[o][3]));
      ob[oc * 256] = (float)fmax(best + (double)sB2[oc], 0.0);
    }
  }
}

// ---------------------------------------------------------------------------
// Split-K NT GEMM, f32 inputs, f64 accumulate, f64 partial output.
// P[s][m*N+n] = sum_{k in chunk s} A[m,k]*B[n,k]  (f64, k ascending)
// 64x64 tile, BK=16, 256 threads, per-thread 4x4 with 2+2 split columns so
// inner ds_read_b128s cover contiguous 256B (2-way bank alias = free).
// LDS tiles f64 (convert once at staging), row stride 66 (staging 2-way).
// ---------------------------------------------------------------------------
__global__ __launch_bounds__(256) void gemm_nt_f64_partial(
    const float* __restrict__ A, const float* __restrict__ B,
    double* __restrict__ P, int M, int N, int K, int Kc) {
  __shared__ double As[16][66];
  __shared__ double Bs[16][66];

  const int t = threadIdx.x;
  const int n0 = blockIdx.x * 64;
  const int m0 = blockIdx.y * 64;
  const int s  = blockIdx.z;
  const int kb = s * Kc;
  const int lm = t >> 2;            // 0..63 staging row
  const int lk4 = (t & 3) * 4;      // 0,4,8,12 staging k offset
  const int ty = t >> 4;            // 0..15
  const int tx = t & 15;            // 0..15

  double acc[4][4];
#pragma unroll
  for (int i = 0; i < 4; ++i)
#pragma unroll
    for (int j = 0; j < 4; ++j) acc[i][j] = 0.0;

  for (int k0 = kb; k0 < kb + Kc; k0 += 16) {
    const float4 av = *(const float4*)&A[(size_t)(m0 + lm) * K + k0 + lk4];
    const float4 bv = *(const float4*)&B[(size_t)(n0 + lm) * K + k0 + lk4];
    __syncthreads();
    As[lk4 + 0][lm] = (double)av.x; As[lk4 + 1][lm] = (double)av.y;
    As[lk4 + 2][lm] = (double)av.z; As[lk4 + 3][lm] = (double)av.w;
    Bs[lk4 + 0][lm] = (double)bv.x; Bs[lk4 + 1][lm] = (double)bv.y;
    Bs[lk4 + 2][lm] = (double)bv.z; Bs[lk4 + 3][lm] = (double)bv.w;
    __syncthreads();
#pragma unroll
    for (int k = 0; k < 16; ++k) {
      const double2 a01 = *(const double2*)&As[k][2 * ty];
      const double2 a23 = *(const double2*)&As[k][32 + 2 * ty];
      const double2 b01 = *(const double2*)&Bs[k][2 * tx];
      const double2 b23 = *(const double2*)&Bs[k][32 + 2 * tx];
      const double ar[4] = {a01.x, a01.y, a23.x, a23.y};
      const double br[4] = {b01.x, b01.y, b23.x, b23.y};
#pragma unroll
      for (int i = 0; i < 4; ++i)
#pragma unroll
        for (int j = 0; j < 4; ++j)
          acc[i][j] = fma(ar[i], br[j], acc[i][j]);
    }
  }

  double* Pp = P + (size_t)s * M * N;
  const int rows[4] = {m0 + 2 * ty, m0 + 2 * ty + 1,
                       m0 + 32 + 2 * ty, m0 + 32 + 2 * ty + 1};
  const int c0 = n0 + 2 * tx, c1 = n0 + 32 + 2 * tx;
#pragma unroll
  for (int i = 0; i < 4; ++i) {
    *(double2*)&Pp[(size_t)rows[i] * N + c0] =
        make_double2(acc[i][0], acc[i][1]);
    *(double2*)&Pp[(size_t)rows[i] * N + c1] =
        make_double2(acc[i][2], acc[i][3]);
  }
}

// ---------------------------------------------------------------------------
// Reduce S f64 partials (fixed ascending order) + R2's exact tanh epilogue:
// zg = f32(sum); z = zg + bias[n] (f32); C = f32(tanh(f64(z)))
// ---------------------------------------------------------------------------
__global__ __launch_bounds__(256) void reduce_tanh(
    const double* __restrict__ P, int S, const float* __restrict__ bias,
    float* __restrict__ C, int N, int total) {
  const int idx = blockIdx.x * 256 + threadIdx.x;
  if (idx >= total) return;
  double sum = 0.0;
  for (int s = 0; s < S; ++s) sum += P[(size_t)s * total + idx];
  const float zg = (float)sum;
  const float z = zg + bias[idx % N];
  C[idx] = (float)tanh((double)z);
}

// ---------------------------------------------------------------------------
// Reduce partials + R2's exact adjacency epilogue on the f32 grid:
// g = f32(sum); fid = g*g; 0.8f/0.6f cutoffs; diag zeroed.
// ---------------------------------------------------------------------------
__global__ __launch_bounds__(256) void reduce_adj(
    const double* __restrict__ P, int S, float* __restrict__ adj, int N) {
  const int idx = blockIdx.x * 256 + threadIdx.x;
  const int total = N * N;
  if (idx >= total) return;
  double sum = 0.0;
  for (int s = 0; s < S; ++s) sum += P[(size_t)s * total + idx];
  const float g = (float)sum;
  const float fid = g * g;
  float v = (fid >= 0.8f) ? 1.0f : ((fid >= 0.6f) ? 0.5f : 0.0f);
  if (idx / N == idx % N) v = 0.0f;
  adj[idx] = v;
}

// ---------------------------------------------------------------------------
// Row L2-normalize on the f32 grid (unchanged from R2).
// ---------------------------------------------------------------------------
__global__ __launch_bounds__(256) void rownorm(
    const float* __restrict__ last, float* __restrict__ nrm) {
  const int b = blockIdx.x;
  const int t = threadIdx.x;
  const float v = last[(size_t)b * 256 + t];
  const float sq = v * v;
  double s = (double)sq;
#pragma unroll
  for (int o = 32; o > 0; o >>= 1) s += __shfl_down(s, o);
  __shared__ double red[4];
  if ((t & 63) == 0) red[t >> 6] = s;
  __syncthreads();
  const double total = red[0] + red[1] + red[2] + red[3];
  const float s32 = (float)total;
  const float den = sqrtf(s32) + 1e-12f;
  nrm[(size_t)b * 256 + t] = v / den;
}

// ---------------------------------------------------------------------------
// BatchNorm1d training mode (unchanged from R2).
// ---------------------------------------------------------------------------
__global__ __launch_bounds__(256) void bn_stats(
    const float* __restrict__ last, const float* __restrict__ gamma,
    const float* __restrict__ beta, float* __restrict__ out) {
  const int j = blockIdx.x;
  const int t = threadIdx.x;
  double v[4];
  double s = 0.0;
#pragma unroll
  for (int i = 0; i < 4; ++i) {
    v[i] = (double)last[(size_t)(i * 256 + t) * 256 + j];
    s += v[i];
  }
#pragma unroll
  for (int o = 32; o > 0; o >>= 1) s += __shfl_down(s, o);
  __shared__ double red[4];
  if ((t & 63) == 0) red[t >> 6] = s;
  __syncthreads();
  const double mean = (red[0] + red[1] + red[2] + red[3]) * (1.0 / 1024.0);
  double q = 0.0;
#pragma unroll
  for (int i = 0; i < 4; ++i) {
    const double d = v[i] - mean;
    q += d * d;
  }
#pragma unroll
  for (int o = 32; o > 0; o >>= 1) q += __shfl_down(q, o);
  __syncthreads();
  if ((t & 63) == 0) red[t >> 6] = q;
  __syncthreads();
  const double var = (red[0] + red[1] + red[2] + red[3]) * (1.0 / 1024.0);
  const double g = (double)gamma[j] / sqrt(var + 1e-5);
  const double be = (double)beta[j];
#pragma unroll
  for (int i = 0; i < 4; ++i)
    out[(size_t)(i * 256 + t) * 256 + j] = (float)((v[i] - mean) * g + be);
}

// ---------------------------------------------------------------------------
extern "C" void kernel_launch(void* const* d_in, const int* in_sizes, int n_in,
                              void* d_out, int out_size, void* d_ws,
                              size_t ws_size, hipStream_t stream) {
  const float* x     = (const float*)d_in[0];
  const float* cw1   = (const float*)d_in[1];
  const float* cb1   = (const float*)d_in[2];
  const float* cw2   = (const float*)d_in[3];
  const float* cb2   = (const float*)d_in[4];
  const float* w1    = (const float*)d_in[5];   // [1024,4096]
  const float* b1    = (const float*)d_in[6];
  const float* w2    = (const float*)d_in[7];   // [256,1024]
  const float* b2    = (const float*)d_in[8];
  const float* gamma = (const float*)d_in[9];
  const float* beta  = (const float*)d_in[10];

  float* outp = (float*)d_out;            // [1024,256]
  float* adj  = outp + 1024 * 256;        // [1024,1024]

  float* ws   = (float*)d_ws;
  float* flat = ws;                       // [1024,4096] @0        16.78 MB
  float* h1   = ws + 4194304;             // [1024,1024]            4.19 MB
  float* last = ws + 5242880;             // [1024,256]             1.05 MB
  float* nrm  = ws + 5505024;             // [1024,256]             1.05 MB
  double* part = (double*)(ws + 5767168); // partials @23.07 MB

  // Split factor for GEMM1 gated on ws_size (deterministic across calls).
  // S=4 partials: 4 * 1M * 8B = 33.55 MB -> total 56.62 MB.
  // S=2 fallback: total 39.85 MB (< 46.1 MB proven available in R1).
  const size_t base = 5767168ull * 4ull;
  const int S1 = (ws_size >= base + 4ull * 1024 * 1024 * 8) ? 4 : 2;

  conv_fused<<<1024, 256, 0, stream>>>(x, cw1, cb1, cw2, cb2, flat);

  // h1 = tanh(flat @ w1^T + b1)   [1024,1024], K=4096, split-K S1
  gemm_nt_f64_partial<<<dim3(16, 16, S1), 256, 0, stream>>>(
      flat, w1, part, 1024, 1024, 4096, 4096 / S1);
  reduce_tanh<<<4096, 256, 0, stream>>>(part, S1, b1, h1, 1024, 1024 * 1024);

  // last = tanh(h1 @ w2^T + b2)   [1024,256], K=1024, split-K 4 (8.39 MB)
  gemm_nt_f64_partial<<<dim3(4, 16, 4), 256, 0, stream>>>(
      h1, w2, part, 1024, 256, 1024, 256);
  reduce_tanh<<<1024, 256, 0, stream>>>(part, 4, b2, last, 256, 1024 * 256);

  rownorm<<<1024, 256, 0, stream>>>(last, nrm);

  // adj = thr((nrm @ nrm^T)^2), zero diag; K=256, split-K 2 (16.78 MB)
  gemm_nt_f64_partial<<<dim3(16, 16, 2), 256, 0, stream>>>(
      nrm, nrm, part, 1024, 1024, 256, 128);
  reduce_adj<<<4096, 256, 0, stream>>>(part, 2, adj, 1024);

  bn_stats<<<256, 256, 0, stream>>>(last, gamma, beta, outp);
}